// Round 7
// baseline (278.289 us; speedup 1.0000x reference)
//
#include <hip/hip_runtime.h>

// Problem constants: B=16, C=256, H=96, W=96, REP_K=3
#define B_   16
#define C_   256
#define HH   96
#define WW   96
#define TPB  64    // ONE wave per block: independent pipeline, no lockstep

typedef _Float16 half8 __attribute__((ext_vector_type(8)));
typedef float   f32x16 __attribute__((ext_vector_type(16)));

// Circulant MFMA formulation (R4/R6-verified numerics & layouts):
//   out[h,w] = sum_j effw[(j-h) mod 96] * (x[j,w] + pe[j]) + bias
// f16 two-term split (hh+lh+hl) -> ~fp32 accuracy.
//
// R6 was latency-bound: 3-wave lockstep blocks at 4 blocks/CU serialized
// stage->compute->store per block. Now: 1-wave workgroups, 12.75 KB LDS
// -> 12 independent blocks/CU, each at a different pipeline phase; one
// wave's HBM latency hides under 11 others' compute.
__global__ __launch_bounds__(TPB) void fused_circ_conv_mfma(
    const float* __restrict__ x,
    const float* __restrict__ meta_pe,
    const float* __restrict__ weight,
    const float* __restrict__ bias,
    const float* __restrict__ rep_weight,
    float* __restrict__ out)
{
    __shared__ __align__(16) float sX[HH][32];   // 12 KB: this wave's 32-col slice
    __shared__ float sW[2 * HH];                 // 768 B: doubled effw

    const int lane = threadIdx.x;                // 0..63
    const int blk  = blockIdx.x;                 // s*4096 + (b*256+c)
    const int bc   = blk & (B_ * C_ - 1);
    const int s    = blk >> 12;                  // col-slice 0..2
    const int c    = bc & (C_ - 1);
    const size_t base = (size_t)bc * (HH * WW);

    const int r32 = lane & 31;                   // A-row / B-col within 32
    const int g   = lane >> 5;                   // k-half 0/1

    // --- stage doubled effective weights: 3 entries per lane ---
#pragma unroll
    for (int t = 0; t < 3; ++t) {
        int u = lane + TPB * t;                  // 0..191
        int k = (u < HH) ? u : u - HH;
        float w_ = weight[c * HH + k];
        if (k < 3) w_ += rep_weight[c * 3 + k];
        sW[u] = w_;
    }

    // --- stage 96x32 slice of (x+pe): 12 x global_load_dwordx4 (12 KB in flight) ---
    {
        const int q  = lane & 7;                 // col-quad
        const int jr = lane >> 3;                // row within 8-row group
        const float* __restrict__ xg = x + base + s * 32 + q * 4;
        const float* __restrict__ pe = meta_pe + c * HH;
#pragma unroll
        for (int t = 0; t < 12; ++t) {
            const int j = t * 8 + jr;
            float4 v = *(const float4*)(xg + (size_t)j * WW);
            float m = pe[j];
            v.x += m; v.y += m; v.z += m; v.w += m;
            *(float4*)(&sX[j][q * 4]) = v;       // 1 KB contiguous per instr
        }
    }
    __syncthreads();   // single-wave: compiles to a waitcnt, no cross-wave stall

    // --- fragments. A is circulant: 6 distinct frags (frag(m,kt)=frag(0,(kt-2m)%6)).
    // A reads: 32 consecutive (descending) sW words/lane-group, 2-way over g -> free.
    // B reads: row stride 32 words -> bank = r32, conflict-free; 2-way over g -> free.
    half8 ah[6], al[6], bh[6], bl[6];
#pragma unroll
    for (int t = 0; t < 6; ++t) {
        const float* wp = sW + (96 + t * 16 + g * 8 - r32);   // idx in [65,191]
#pragma unroll
        for (int e = 0; e < 8; ++e) {
            float w_ = wp[e];
            _Float16 h = (_Float16)w_;
            ah[t][e] = h;
            al[t][e] = (_Float16)(w_ - (float)h);
            float v = sX[t * 16 + g * 8 + e][r32];
            _Float16 hb = (_Float16)v;
            bh[t][e] = hb;
            bl[t][e] = (_Float16)(v - (float)hb);
        }
    }

    const float bv = bias[c];
    float* __restrict__ op = out + base + (s * 32 + r32);

    // --- 3 m-tiles x 6 k-tiles x 3 split-terms = 54 MFMA ---
#pragma unroll
    for (int m = 0; m < 3; ++m) {
        f32x16 acc;
#pragma unroll
        for (int i = 0; i < 16; ++i) acc[i] = 0.f;
#pragma unroll
        for (int kt = 0; kt < 6; ++kt) {
            const int t = (kt + 6 - 2 * m) % 6;  // compile-time after unroll
            acc = __builtin_amdgcn_mfma_f32_32x32x16_f16(ah[t], bh[kt], acc, 0, 0, 0);
            acc = __builtin_amdgcn_mfma_f32_32x32x16_f16(al[t], bh[kt], acc, 0, 0, 0);
            acc = __builtin_amdgcn_mfma_f32_32x32x16_f16(ah[t], bl[kt], acc, 0, 0, 0);
        }
        // C/D layout (R4-verified): col = lane&31, row = (reg&3)+8*(reg>>2)+4*g
#pragma unroll
        for (int reg = 0; reg < 16; ++reg) {
            int row = m * 32 + (reg & 3) + 8 * (reg >> 2) + 4 * g;
            op[(size_t)row * WW] = acc[reg] + bv;   // 2 x 128B segments per instr
        }
    }
}

extern "C" void kernel_launch(void* const* d_in, const int* in_sizes, int n_in,
                              void* d_out, int out_size, void* d_ws, size_t ws_size,
                              hipStream_t stream) {
    const float* x          = (const float*)d_in[0];
    const float* meta_pe    = (const float*)d_in[1];
    const float* weight     = (const float*)d_in[2];
    const float* bias       = (const float*)d_in[3];
    const float* rep_weight = (const float*)d_in[4];
    float* out = (float*)d_out;

    fused_circ_conv_mfma<<<dim3(3 * B_ * C_), dim3(TPB), 0, stream>>>(
        x, meta_pe, weight, bias, rep_weight, out);
}